// Round 1
// baseline (37483.734 us; speedup 1.0000x reference)
//
#include <hip/hip_runtime.h>
#include <math.h>

#define N_ 128
#define T_ 512
#define D_ 1024
#define H_ 1024

// ---------------------------------------------------------------------------
// Phase 1: xw = x @ Wx + b -> d_out (same (N,T,H) layout). Unchanged.
// ---------------------------------------------------------------------------
__global__ __launch_bounds__(256) void gemm_xw(
    const float* __restrict__ A,    // (M, D_) row-major
    const float* __restrict__ B,    // (D_, H_) row-major
    const float* __restrict__ bias, // (H_)
    float* __restrict__ C)          // (M, H_) row-major
{
    __shared__ float As[8][128];
    __shared__ float Bs[8][128];

    const int tid = threadIdx.x;
    const int m0 = blockIdx.x * 128;
    const int n0 = blockIdx.y * 128;

    const int la_m = tid & 127;
    const int la_k = (tid >> 7) * 4;
    const int lb_k = tid >> 5;
    const int lb_n = (tid & 31) * 4;

    const int tx = tid & 15;
    const int ty = tid >> 4;
    const int cm = ty * 8;
    const int cn = tx * 8;

    float acc[8][8];
#pragma unroll
    for (int i = 0; i < 8; i++)
#pragma unroll
        for (int j = 0; j < 8; j++) acc[i][j] = 0.f;

    const float* aptr = A + (long)(m0 + la_m) * D_ + la_k;
    const float* bptr = B + (long)lb_k * H_ + n0 + lb_n;

    for (int k0 = 0; k0 < D_; k0 += 8) {
        float4 av = *(const float4*)(aptr + k0);
        float4 bv = *(const float4*)(bptr + (long)k0 * H_);
        As[la_k + 0][la_m] = av.x;
        As[la_k + 1][la_m] = av.y;
        As[la_k + 2][la_m] = av.z;
        As[la_k + 3][la_m] = av.w;
        *(float4*)&Bs[lb_k][lb_n] = bv;
        __syncthreads();
#pragma unroll
        for (int k = 0; k < 8; k++) {
            float a0[8], b0[8];
            *(float4*)&a0[0] = *(const float4*)&As[k][cm];
            *(float4*)&a0[4] = *(const float4*)&As[k][cm + 4];
            *(float4*)&b0[0] = *(const float4*)&Bs[k][cn];
            *(float4*)&b0[4] = *(const float4*)&Bs[k][cn + 4];
#pragma unroll
            for (int i = 0; i < 8; i++)
#pragma unroll
                for (int j = 0; j < 8; j++)
                    acc[i][j] = fmaf(a0[i], b0[j], acc[i][j]);
        }
        __syncthreads();
    }

#pragma unroll
    for (int i = 0; i < 8; i++) {
        long row = (long)(m0 + cm + i) * H_ + n0;
#pragma unroll
        for (int j = 0; j < 8; j += 4) {
            float4 v;
            v.x = acc[i][j + 0] + bias[n0 + cn + j + 0];
            v.y = acc[i][j + 1] + bias[n0 + cn + j + 1];
            v.z = acc[i][j + 2] + bias[n0 + cn + j + 2];
            v.w = acc[i][j + 3] + bias[n0 + cn + j + 3];
            *(float4*)&C[row + cn + j] = v;
        }
    }
}

// ---------------------------------------------------------------------------
// Phase 2 (persistent): one cooperative kernel runs all 512 timesteps.
// Grid 256 = 8 m-tiles (16 rows) x 32 n-tiles (32 cols), 1 block/CU (LDS>80KB).
// Each thread holds its Wh slice (32 k x 4 cols = 32 float4 = 128 VGPRs) in
// registers for the whole scan: Wh is fetched from memory exactly once.
// Thread map: c4 = tid&7 (4-col group), ks = tid>>3 (32-k slice).
// k order within a slice is rotated by ks_lo=(ks&7) so the per-wave LDS reads
// of the staged h tile hit 32 distinct banks (conflict-free ds_read_b128);
// the Wh register load uses the SAME rotation so register indices stay static.
// Reduction over the 32 k-slices: shfl_xor butterfly over lanes 8/16/32
// (within-wave, ks_lo) + 8 KB LDS pass across the 4 waves.
// Cross-block sync: per-m-group (32 blocks) barrier with agent-scope atomics.
// ---------------------------------------------------------------------------
__global__ __launch_bounds__(256, 1) void rnn_persist(
    const float* __restrict__ h0,
    const float* __restrict__ Wh,
    float* __restrict__ out,
    int* ctr)
{
    __shared__ __align__(16) float hs[16][1024];   // 64 KB h tile
    __shared__ float4 red[4][16][8];               // 8 KB cross-wave partials
    __shared__ float ldspad[2304];                 // 9 KB pad -> 82.9 KB total,
                                                   // forces 1 block/CU
    const int tid = threadIdx.x;
    // keep pad allocated; condition is never true at runtime (d_ws is aligned)
    if (((unsigned long long)(const void*)ctr) & 1ull) ldspad[tid] = 0.f;

    const int mt = blockIdx.x >> 5;
    const int m0 = mt << 4;
    const int n0 = (blockIdx.x & 31) << 5;

    const int c4    = tid & 7;    // float4 column group within the 32-col tile
    const int ks    = tid >> 3;   // 0..31 : 32-wide k slice
    const int ks_lo = ks & 7;
    const int lane  = tid & 63;
    const int wv    = tid >> 6;

    // ---- Wh slice -> registers (k order rotated by ks_lo; loaded ONCE) ----
    float4 wh[32];
#pragma unroll
    for (int q = 0; q < 8; q++) {
        const int kb = ks * 32 + ((q + ks_lo) & 7) * 4;
#pragma unroll
        for (int j = 0; j < 4; j++)
            wh[q * 4 + j] = *(const float4*)&Wh[(long)(kb + j) * H_ + n0 + c4 * 4];
    }

    // finalize-thread coordinates (tid<128 writes the 16x32 output tile)
    const int fr = tid >> 3;
    const int fc = tid & 7;

    for (int t = 0; t < T_; t++) {
        const float* hp;
        long hstr;
        if (t == 0) { hp = h0;                       hstr = H_; }
        else        { hp = out + (long)(t - 1) * H_; hstr = (long)T_ * H_; }

        // ---- stage h tile: 16 rows x 4 KB, async global->LDS (linear) ----
#pragma unroll
        for (int i = 0; i < 16; i++) {
            const float* src = hp + (long)(m0 + i) * hstr + tid * 4;
            __builtin_amdgcn_global_load_lds(
                (const __attribute__((address_space(1))) void*)src,
                (__attribute__((address_space(3))) void*)&hs[i][tid * 4],
                16, 0, 0);
        }
        // prefetch this step's xw while staging drains (phase-1 data, stable)
        const long fo = (long)(m0 + fr) * (T_ * H_) + (long)t * H_ + n0 + fc * 4;
        float4 xw4 = make_float4(0.f, 0.f, 0.f, 0.f);
        if (tid < 128) xw4 = *(const float4*)&out[fo];
        __syncthreads();   // drains vmcnt: hs + xw4 both ready

        // ---- partial GEMM: 16 rows x 4 cols x 32 k, Wh in registers ----
        float4 acc[16];
#pragma unroll
        for (int r = 0; r < 16; r++) acc[r] = make_float4(0.f, 0.f, 0.f, 0.f);

        const float* hbase = &hs[0][ks * 32];
#pragma unroll
        for (int q = 0; q < 8; q++) {
            const float4* h4 = (const float4*)(hbase + ((q + ks_lo) & 7) * 4);
            const float4 w0 = wh[q * 4 + 0];
            const float4 w1 = wh[q * 4 + 1];
            const float4 w2 = wh[q * 4 + 2];
            const float4 w3 = wh[q * 4 + 3];
#pragma unroll
            for (int r = 0; r < 16; r++) {
                const float4 hv = h4[r * 256];   // ds_read_b128, imm offset
                acc[r].x = fmaf(hv.x, w0.x, acc[r].x);
                acc[r].y = fmaf(hv.x, w0.y, acc[r].y);
                acc[r].z = fmaf(hv.x, w0.z, acc[r].z);
                acc[r].w = fmaf(hv.x, w0.w, acc[r].w);
                acc[r].x = fmaf(hv.y, w1.x, acc[r].x);
                acc[r].y = fmaf(hv.y, w1.y, acc[r].y);
                acc[r].z = fmaf(hv.y, w1.z, acc[r].z);
                acc[r].w = fmaf(hv.y, w1.w, acc[r].w);
                acc[r].x = fmaf(hv.z, w2.x, acc[r].x);
                acc[r].y = fmaf(hv.z, w2.y, acc[r].y);
                acc[r].z = fmaf(hv.z, w2.z, acc[r].z);
                acc[r].w = fmaf(hv.z, w2.w, acc[r].w);
                acc[r].x = fmaf(hv.w, w3.x, acc[r].x);
                acc[r].y = fmaf(hv.w, w3.y, acc[r].y);
                acc[r].z = fmaf(hv.w, w3.z, acc[r].z);
                acc[r].w = fmaf(hv.w, w3.w, acc[r].w);
            }
        }

        // ---- reduce 32 k-slices: butterfly over ks_lo (lane bits 3..5) ----
#pragma unroll
        for (int r = 0; r < 16; r++) {
            float4 a = acc[r];
            a.x += __shfl_xor(a.x, 8);  a.y += __shfl_xor(a.y, 8);
            a.z += __shfl_xor(a.z, 8);  a.w += __shfl_xor(a.w, 8);
            a.x += __shfl_xor(a.x, 16); a.y += __shfl_xor(a.y, 16);
            a.z += __shfl_xor(a.z, 16); a.w += __shfl_xor(a.w, 16);
            a.x += __shfl_xor(a.x, 32); a.y += __shfl_xor(a.y, 32);
            a.z += __shfl_xor(a.z, 32); a.w += __shfl_xor(a.w, 32);
            if (lane < 8) red[wv][r][lane] = a;   // lane==c4, ks_lo==0
        }
        __syncthreads();

        // ---- finalize: cross-wave sum + xw + tanh, store h_t ----
        if (tid < 128) {
            const float4 s0 = red[0][fr][fc];
            const float4 s1 = red[1][fr][fc];
            const float4 s2 = red[2][fr][fc];
            const float4 s3 = red[3][fr][fc];
            float4 res;
            res.x = tanhf(xw4.x + s0.x + s1.x + s2.x + s3.x);
            res.y = tanhf(xw4.y + s0.y + s1.y + s2.y + s3.y);
            res.z = tanhf(xw4.z + s0.z + s1.z + s2.z + s3.z);
            res.w = tanhf(xw4.w + s0.w + s1.w + s2.w + s3.w);
            *(float4*)&out[fo] = res;
        }

        // ---- m-group barrier: 32 blocks sharing rows [m0, m0+16) ----
        if (t < T_ - 1) {
            __threadfence();     // agent-scope release of h_t stores
            __syncthreads();
            if (tid == 0) {
                __hip_atomic_fetch_add(&ctr[mt], 1, __ATOMIC_RELEASE,
                                       __HIP_MEMORY_SCOPE_AGENT);
                const int tgt = 32 * (t + 1);
                while (__hip_atomic_load(&ctr[mt], __ATOMIC_ACQUIRE,
                                         __HIP_MEMORY_SCOPE_AGENT) < tgt)
                    __builtin_amdgcn_s_sleep(1);
            }
            __syncthreads();
        }
    }
}

// ---------------------------------------------------------------------------
// Fallback per-step kernel (only used if cooperative launch is unavailable).
// ---------------------------------------------------------------------------
__global__ __launch_bounds__(256) void rnn_step(
    const float* __restrict__ hprev, long hstride,
    const float* __restrict__ Wh,
    float* __restrict__ out_t)
{
    __shared__ float hs[16][1028];
    __shared__ float red[16][33];

    const int tid = threadIdx.x;
    const int m0 = (blockIdx.x >> 5) * 16;
    const int n0 = (blockIdx.x & 31) * 32;

    {
        const int lr = tid >> 4;
        const int lc = (tid & 15) * 4;
        const float* src = hprev + (long)(m0 + lr) * hstride;
#pragma unroll
        for (int i = 0; i < 16; i++) {
            *(float4*)&hs[lr][lc + i * 64] = *(const float4*)&src[lc + i * 64];
        }
    }
    __syncthreads();

    const int ks = tid >> 7;
    const int r  = (tid >> 3) & 15;
    const int cg = tid & 7;

    const float* wp   = Wh + (long)(ks * 512) * H_ + n0 + cg * 4;
    const float* hrow = &hs[r][ks * 512];

    float4 acc = make_float4(0.f, 0.f, 0.f, 0.f);
#pragma unroll 8
    for (int k = 0; k < 512; k++) {
        float hv = hrow[k];
        float4 w = *(const float4*)(wp + (long)k * H_);
        acc.x = fmaf(hv, w.x, acc.x);
        acc.y = fmaf(hv, w.y, acc.y);
        acc.z = fmaf(hv, w.z, acc.z);
        acc.w = fmaf(hv, w.w, acc.w);
    }

    if (ks == 1) {
        red[r][cg * 4 + 0] = acc.x;
        red[r][cg * 4 + 1] = acc.y;
        red[r][cg * 4 + 2] = acc.z;
        red[r][cg * 4 + 3] = acc.w;
    }
    __syncthreads();
    if (ks == 0) {
        long o = (long)(m0 + r) * (T_ * H_) + n0 + cg * 4;
        float4 xw4 = *(const float4*)&out_t[o];
        float4 res;
        res.x = tanhf(xw4.x + acc.x + red[r][cg * 4 + 0]);
        res.y = tanhf(xw4.y + acc.y + red[r][cg * 4 + 1]);
        res.z = tanhf(xw4.z + acc.z + red[r][cg * 4 + 2]);
        res.w = tanhf(xw4.w + acc.w + red[r][cg * 4 + 3]);
        *(float4*)&out_t[o] = res;
    }
}

// ---------------------------------------------------------------------------
extern "C" void kernel_launch(void* const* d_in, const int* in_sizes, int n_in,
                              void* d_out, int out_size, void* d_ws, size_t ws_size,
                              hipStream_t stream) {
    const float* x  = (const float*)d_in[0]; // (N, T, D)
    const float* h0 = (const float*)d_in[1]; // (N, H)
    const float* Wx = (const float*)d_in[2]; // (D, H)
    const float* Wh = (const float*)d_in[3]; // (H, H)
    const float* b  = (const float*)d_in[4]; // (H)
    float* out = (float*)d_out;              // (N, T, H)
    int* ctr = (int*)d_ws;                   // 8 m-group barrier counters

    // Phase 1: xw -> d_out
    dim3 g1((N_ * T_) / 128, H_ / 128); // 512 x 8
    gemm_xw<<<g1, 256, 0, stream>>>(x, Wx, b, out);

    // zero barrier counters (graph-capture-legal, re-run each replay)
    hipMemsetAsync(ctr, 0, 32, stream);

    // Phase 2: persistent cooperative scan
    const float* h0p = h0;
    const float* whp = Wh;
    float* outp = out;
    int* ctrp = ctr;
    void* args[] = {(void*)&h0p, (void*)&whp, (void*)&outp, (void*)&ctrp};
    hipError_t e = hipLaunchCooperativeKernel(
        (const void*)rnn_persist, dim3(256), dim3(256), args, 0, stream);

    if (e != hipSuccess) {
        // fallback: per-step launches (previous verified path)
        for (int t = 0; t < T_; t++) {
            const float* hpv = (t == 0) ? h0 : (out + (long)(t - 1) * H_);
            long hstride = (t == 0) ? (long)H_ : (long)T_ * H_;
            rnn_step<<<dim3(256), 256, 0, stream>>>(hpv, hstride, Wh,
                                                    out + (long)t * H_);
        }
    }
}